// Round 1
// 539.348 us; speedup vs baseline: 1.0089x; 1.0089x over previous
//
#include <hip/hip_runtime.h>
#include <stdint.h>

// HierarchicalGRU on MI355X. B=16384, IN=4096, H=128, NOPT=64.
// Round 5: fuse attn+gru0+gru1 into ONE barrier-free kernel.
//  - obs A-fragments loaded direct-to-register (fp32->bf16 in reg), each byte read once
//  - all B operands (WaT + GRU weights) loaded direct from global/L2 (proven k_gru0 pattern)
//  - wave-private LDS tiles only (attn 4KB + hc 4KB per wave): ZERO __syncthreads
//  - h0/h1: frags from global + elementwise term as fp32 (more accurate than old bf16 path)

typedef __attribute__((ext_vector_type(8))) short bf16x8;
typedef __attribute__((ext_vector_type(4))) float f32x4;
typedef __attribute__((ext_vector_type(8))) float f32x8;

#define INDIM 4096
#define H 128
#define NOPT 64

// workspace layout (uint16 element offsets), bf16 contents
#define WS_WAT    0u        // [128, 4096]
#define WS_WIH0T  524288u   // [384, 128]
#define WS_WHH0T  573440u   // [384, 128]
#define WS_WIH1T  622592u   // [384, 256]
#define WS_WHH1T  720896u   // [384, 128]
#define WS_WV0T   770048u   // [64, 128]
#define WS_WV1T   778240u   // [64, 128]
#define WS_WT0T   786432u   // [64, 128]

// output layout (fp32 element offsets): v0[B,64], term_p[B,1], v1[B,64], h0n[B,128], h1n[B,128]
#define OUT_V0    0u
#define OUT_TERMP 1048576u
#define OUT_V1    1064960u
#define OUT_H0N   2113536u
#define OUT_H1N   4210688u

static __device__ __forceinline__ uint16_t f2bf(float f) {
  union { float f; uint32_t i; } x; x.f = f;
  uint32_t r = x.i + 0x7fffu + ((x.i >> 16) & 1u);
  return (uint16_t)(r >> 16);
}
static __device__ __forceinline__ float sigm(float x) { return 1.0f / (1.0f + __expf(-x)); }
static __device__ __forceinline__ float fast_tanh(float x) {
  float e = __expf(2.0f * x);          // e=inf -> 1, e=0 -> -1: saturates correctly
  return 1.0f - 2.0f / (e + 1.0f);
}
static __device__ __forceinline__ f32x4 mfma16(bf16x8 a, bf16x8 b, f32x4 c) {
  return __builtin_amdgcn_mfma_f32_16x16x32_bf16(a, b, c, 0, 0, 0);
}
static __device__ __forceinline__ bf16x8 cvt8(f32x8 v) {
  bf16x8 r;
#pragma unroll
  for (int j = 0; j < 8; ++j) r[j] = (short)f2bf(v[j]);
  return r;
}

// ---------------- K0: weight transpose+convert  W[K,N] fp32 -> WT[N,K] bf16 ----------------
__global__ void k_transpose(const float* __restrict__ Wa,
                            const float* __restrict__ Wih0,
                            const float* __restrict__ Whh0,
                            const float* __restrict__ Wih1,
                            const float* __restrict__ Whh1,
                            const float* __restrict__ Wv0,
                            const float* __restrict__ Wv1,
                            const float* __restrict__ Wt0,
                            uint16_t* __restrict__ ws) {
  int blk = blockIdx.x;
  const float* in; uint16_t* out; int ksh; int N; int base;
  if (blk < 2048)      { in = Wa;   out = ws + WS_WAT;   ksh = 12; N = 128; base = 0; }
  else if (blk < 2240) { in = Wih0; out = ws + WS_WIH0T; ksh = 7;  N = 384; base = 2048; }
  else if (blk < 2432) { in = Whh0; out = ws + WS_WHH0T; ksh = 7;  N = 384; base = 2240; }
  else if (blk < 2816) { in = Wih1; out = ws + WS_WIH1T; ksh = 8;  N = 384; base = 2432; }
  else if (blk < 3008) { in = Whh1; out = ws + WS_WHH1T; ksh = 7;  N = 384; base = 2816; }
  else if (blk < 3040) { in = Wv0;  out = ws + WS_WV0T;  ksh = 7;  N = 64;  base = 3008; }
  else if (blk < 3072) { in = Wv1;  out = ws + WS_WV1T;  ksh = 7;  N = 64;  base = 3040; }
  else                 { in = Wt0;  out = ws + WS_WT0T;  ksh = 7;  N = 64;  base = 3072; }
  int e = (blk - base) * 256 + (int)threadIdx.x;
  int n = e >> ksh;
  int k = e & ((1 << ksh) - 1);
  out[e] = f2bf(in[(size_t)k * N + n]);
}

// ---------------- K1: fused attn -> gru0(+v0/term) -> gru1(+v1) ----------------
// 512 blocks x 128 thr; each wave owns 16 rows end-to-end. No __syncthreads.
__launch_bounds__(128)
__global__ void k_fused(const float* __restrict__ obs,
                        const uint16_t* __restrict__ ws,
                        const float* __restrict__ ba,
                        const float* __restrict__ h0,
                        const float* __restrict__ bih0,
                        const float* __restrict__ bhh0,
                        const float* __restrict__ bv0,
                        const float* __restrict__ bt0,
                        const int* __restrict__ chosen,
                        const float* __restrict__ h1,
                        const float* __restrict__ bih1,
                        const float* __restrict__ bhh1,
                        const float* __restrict__ bv1,
                        float* __restrict__ out) {
  // per-wave private tiles: 16 rows x 16 k-slots x 8 elts, XOR-swizzled (kb ^ row)
  __shared__ uint16_t sAttn[2][16 * 16 * 8];
  __shared__ uint16_t sHC[2][16 * 16 * 8];
  const uint16_t* WaT   = ws + WS_WAT;
  const uint16_t* Wih0T = ws + WS_WIH0T;
  const uint16_t* Whh0T = ws + WS_WHH0T;
  const uint16_t* Wih1T = ws + WS_WIH1T;
  const uint16_t* Whh1T = ws + WS_WHH1T;
  const uint16_t* Wv0T  = ws + WS_WV0T;
  const uint16_t* Wv1T  = ws + WS_WV1T;
  const uint16_t* Wt0T  = ws + WS_WT0T;
  const int t = threadIdx.x, w = t >> 6, lane = t & 63;
  const int l15 = lane & 15, quad = lane >> 4;
  const int row0 = blockIdx.x * 32 + w * 16;   // wave's first global row
  uint16_t* sX = sAttn[w];
  uint16_t* sC = sHC[w];

  // ---- Phase A: attn = tanh(obs @ WaT^T + ba) for rows row0..row0+15 ----
  f32x4 acc[8] = {};
  {
    const float* arow = obs + (size_t)(row0 + l15) * INDIM + quad * 8;
    const uint16_t* brow = WaT + (size_t)l15 * INDIM + quad * 8;
#pragma unroll 2
    for (int kt = 0; kt < 64; ++kt) {
      const int k0 = kt * 64;
      f32x8 av0 = *(const f32x8*)(arow + k0);        // k = k0 + quad*8 .. +8
      f32x8 av1 = *(const f32x8*)(arow + k0 + 32);   // k = k0+32 + quad*8 .. +8
      bf16x8 a0 = cvt8(av0);
      bf16x8 a1 = cvt8(av1);
#pragma unroll
      for (int nb = 0; nb < 8; ++nb) {
        const uint16_t* bp = brow + (size_t)(nb * 16) * INDIM + k0;
        bf16x8 b0 = *(const bf16x8*)(bp);
        bf16x8 b1 = *(const bf16x8*)(bp + 32);
        acc[nb] = mfma16(a0, b0, acc[nb]);
        acc[nb] = mfma16(a1, b1, acc[nb]);
      }
    }
  }
  // epilogue: tanh+bias, scatter into wave-private LDS tile (A-frag layout)
#pragma unroll
  for (int nb = 0; nb < 8; ++nb) {
    const int col = nb * 16 + l15;
    const float bav = ba[col];
    const int kb = col >> 3;
#pragma unroll
    for (int i = 0; i < 4; ++i) {
      const int r = quad * 4 + i;                    // C/D: col=lane&15, row=quad*4+reg
      sX[(r * 16 + (kb ^ r)) * 8 + (col & 7)] = f2bf(fast_tanh(acc[nb][i] + bav));
    }
  }

  // ---- Phase B: GRU layer 0 + v0/term heads ----
  bf16x8 ax[4], ah[4];
  {
    const float* hrow = h0 + (size_t)(row0 + l15) * H + quad * 8;
#pragma unroll
    for (int ks = 0; ks < 4; ++ks) {
      const int kb = ks * 4 + quad;
      ax[ks] = *(const bf16x8*)&sX[(l15 * 16 + (kb ^ l15)) * 8];
      ah[ks] = cvt8(*(const f32x8*)(hrow + ks * 32));
    }
  }
#pragma unroll
  for (int nb = 0; nb < 8; ++nb) {
    f32x4 air = {}, ahr = {}, aiz = {}, ahz = {}, ain = {}, ahn = {};
    const int nrow = nb * 16 + l15;
#pragma unroll
    for (int ks = 0; ks < 4; ++ks) {
      const int k = ks * 32 + quad * 8;
      bf16x8 b;
      b = *(const bf16x8*)(Wih0T + (size_t)(nrow      ) * H + k); air = mfma16(ax[ks], b, air);
      b = *(const bf16x8*)(Wih0T + (size_t)(nrow + 128) * H + k); aiz = mfma16(ax[ks], b, aiz);
      b = *(const bf16x8*)(Wih0T + (size_t)(nrow + 256) * H + k); ain = mfma16(ax[ks], b, ain);
      b = *(const bf16x8*)(Whh0T + (size_t)(nrow      ) * H + k); ahr = mfma16(ah[ks], b, ahr);
      b = *(const bf16x8*)(Whh0T + (size_t)(nrow + 128) * H + k); ahz = mfma16(ah[ks], b, ahz);
      b = *(const bf16x8*)(Whh0T + (size_t)(nrow + 256) * H + k); ahn = mfma16(ah[ks], b, ahn);
    }
    const int col = nrow;
    const float b_ir = bih0[col],       b_hr = bhh0[col];
    const float b_iz = bih0[col + 128], b_hz = bhh0[col + 128];
    const float b_in = bih0[col + 256], b_hn = bhh0[col + 256];
    const int kb = col >> 3;
#pragma unroll
    for (int i = 0; i < 4; ++i) {
      const int r = quad * 4 + i;
      const int grow = row0 + r;
      const float rr = sigm(air[i] + ahr[i] + b_ir + b_hr);
      const float zz = sigm(aiz[i] + ahz[i] + b_iz + b_hz);
      const float nn = fast_tanh(ain[i] + b_in + rr * (ahn[i] + b_hn));
      const float hv = h0[(size_t)grow * H + col];            // fp32, exact
      const float hnew = (1.0f - zz) * nn + zz * hv;
      out[OUT_H0N + (size_t)grow * H + col] = hnew;
      sC[(r * 16 + (kb ^ r)) * 8 + (col & 7)] = f2bf(0.5f * hnew + 0.25f);  // hc0
    }
  }
  {
    int ch[4];
#pragma unroll
    for (int i = 0; i < 4; ++i) ch[i] = chosen[row0 + quad * 4 + i];
    bf16x8 ac[4];
#pragma unroll
    for (int ks = 0; ks < 4; ++ks) {
      const int kb = ks * 4 + quad;
      ac[ks] = *(const bf16x8*)&sC[(l15 * 16 + (kb ^ l15)) * 8];
    }
#pragma unroll
    for (int vb = 0; vb < 4; ++vb) {
      f32x4 av = {}, at = {};
      const int nrow = vb * 16 + l15;
#pragma unroll
      for (int ks = 0; ks < 4; ++ks) {
        const int k = ks * 32 + quad * 8;
        bf16x8 b;
        b = *(const bf16x8*)(Wv0T + (size_t)nrow * H + k); av = mfma16(ac[ks], b, av);
        b = *(const bf16x8*)(Wt0T + (size_t)nrow * H + k); at = mfma16(ac[ks], b, at);
      }
      const int col = vb * 16 + l15;
      const float bvv = bv0[col], btv = bt0[col];
#pragma unroll
      for (int i = 0; i < 4; ++i) {
        const int grow = row0 + quad * 4 + i;
        out[OUT_V0 + (size_t)grow * NOPT + col] = av[i] + bvv;
        if (ch[i] == col)
          out[OUT_TERMP + grow] = sigm(at[i] + btv);
      }
    }
  }

  // ---- Phase C: GRU layer 1 (x1 = [attn | h1]) + v1 head ----
  bf16x8 ah1[4];
  {
    const float* hrow = h1 + (size_t)(row0 + l15) * H + quad * 8;
#pragma unroll
    for (int ks = 0; ks < 4; ++ks)
      ah1[ks] = cvt8(*(const f32x8*)(hrow + ks * 32));
  }
#pragma unroll
  for (int nb = 0; nb < 8; ++nb) {
    f32x4 air = {}, ahr = {}, aiz = {}, ahz = {}, ain = {}, ahn = {};
    const int nrow = nb * 16 + l15;
#pragma unroll
    for (int ks = 0; ks < 8; ++ks) {   // gi1 over K=256: x1 = [attn | h1]
      const int k = ks * 32 + quad * 8;
      const bf16x8 a = (ks < 4) ? ax[ks] : ah1[ks - 4];
      bf16x8 b;
      b = *(const bf16x8*)(Wih1T + (size_t)(nrow      ) * 256 + k); air = mfma16(a, b, air);
      b = *(const bf16x8*)(Wih1T + (size_t)(nrow + 128) * 256 + k); aiz = mfma16(a, b, aiz);
      b = *(const bf16x8*)(Wih1T + (size_t)(nrow + 256) * 256 + k); ain = mfma16(a, b, ain);
    }
#pragma unroll
    for (int ks = 0; ks < 4; ++ks) {   // gh1 over K=128
      const int k = ks * 32 + quad * 8;
      bf16x8 b;
      b = *(const bf16x8*)(Whh1T + (size_t)(nrow      ) * H + k); ahr = mfma16(ah1[ks], b, ahr);
      b = *(const bf16x8*)(Whh1T + (size_t)(nrow + 128) * H + k); ahz = mfma16(ah1[ks], b, ahz);
      b = *(const bf16x8*)(Whh1T + (size_t)(nrow + 256) * H + k); ahn = mfma16(ah1[ks], b, ahn);
    }
    const int col = nrow;
    const float b_ir = bih1[col],       b_hr = bhh1[col];
    const float b_iz = bih1[col + 128], b_hz = bhh1[col + 128];
    const float b_in = bih1[col + 256], b_hn = bhh1[col + 256];
    const int kb = col >> 3;
#pragma unroll
    for (int i = 0; i < 4; ++i) {
      const int r = quad * 4 + i;
      const int grow = row0 + r;
      const float rr = sigm(air[i] + ahr[i] + b_ir + b_hr);
      const float zz = sigm(aiz[i] + ahz[i] + b_iz + b_hz);
      const float nn = fast_tanh(ain[i] + b_in + rr * (ahn[i] + b_hn));
      const float hv = h1[(size_t)grow * H + col];
      const float hnew = (1.0f - zz) * nn + zz * hv;
      out[OUT_H1N + (size_t)grow * H + col] = hnew;
      sC[(r * 16 + (kb ^ r)) * 8 + (col & 7)] = f2bf(0.5f * hnew + 0.25f);  // hc1 (reuse tile)
    }
  }
  {
    bf16x8 ac[4];
#pragma unroll
    for (int ks = 0; ks < 4; ++ks) {
      const int kb = ks * 4 + quad;
      ac[ks] = *(const bf16x8*)&sC[(l15 * 16 + (kb ^ l15)) * 8];
    }
#pragma unroll
    for (int vb = 0; vb < 4; ++vb) {
      f32x4 av = {};
      const int nrow = vb * 16 + l15;
#pragma unroll
      for (int ks = 0; ks < 4; ++ks) {
        const int k = ks * 32 + quad * 8;
        bf16x8 b = *(const bf16x8*)(Wv1T + (size_t)nrow * H + k);
        av = mfma16(ac[ks], b, av);
      }
      const int col = vb * 16 + l15;
      const float bvv = bv1[col];
#pragma unroll
      for (int i = 0; i < 4; ++i) {
        const int grow = row0 + quad * 4 + i;
        out[OUT_V1 + (size_t)grow * NOPT + col] = av[i] + bvv;
      }
    }
  }
}

extern "C" void kernel_launch(void* const* d_in, const int* in_sizes, int n_in,
                              void* d_out, int out_size, void* d_ws, size_t ws_size,
                              hipStream_t stream) {
  (void)in_sizes; (void)n_in; (void)out_size; (void)ws_size;
  const float* obs    = (const float*)d_in[0];
  const int*   chosen = (const int*)d_in[1];
  const float* h0     = (const float*)d_in[2];
  const float* h1     = (const float*)d_in[3];
  const float* Wa     = (const float*)d_in[4];
  const float* ba     = (const float*)d_in[5];
  const float* Wih0   = (const float*)d_in[6];
  const float* Whh0   = (const float*)d_in[7];
  const float* bih0   = (const float*)d_in[8];
  const float* bhh0   = (const float*)d_in[9];
  const float* Wih1   = (const float*)d_in[10];
  const float* Whh1   = (const float*)d_in[11];
  const float* bih1   = (const float*)d_in[12];
  const float* bhh1   = (const float*)d_in[13];
  const float* Wv0    = (const float*)d_in[14];
  const float* bv0    = (const float*)d_in[15];
  const float* Wv1    = (const float*)d_in[16];
  const float* bv1    = (const float*)d_in[17];
  const float* Wt0    = (const float*)d_in[18];
  const float* bt0    = (const float*)d_in[19];
  uint16_t* ws  = (uint16_t*)d_ws;
  float*    out = (float*)d_out;

  hipLaunchKernelGGL(k_transpose, dim3(3104), dim3(256), 0, stream,
                     Wa, Wih0, Whh0, Wih1, Whh1, Wv0, Wv1, Wt0, ws);
  hipLaunchKernelGGL(k_fused, dim3(512), dim3(128), 0, stream,
                     obs, ws, ba, h0, bih0, bhh0, bv0, bt0, chosen,
                     h1, bih1, bhh1, bv1, out);
}